// Round 7
// baseline (248.930 us; speedup 1.0000x reference)
//
#include <hip/hip_runtime.h>

#define BIG 3.0e38f

typedef float vf4 __attribute__((ext_vector_type(4)));

// ---------------------------------------------------------------------------
// Branchless top-3 insert (strict < keeps lowest index on ties, matching
// top_k). Distances via fmin/v_med3_f32 (3 ops), indices via cndmask off the
// same 3 compares: 3 cmp + 6 csel + 3 min/med vs the old 3 cmp + 10 csel.
// Distance VALUES and tie semantics identical to the old version.
// ---------------------------------------------------------------------------
__device__ __forceinline__ void insert3(float d, int s,
                                        float& d0, float& d1, float& d2,
                                        int& i0, int& i1, int& i2) {
    const bool b0 = d < d0;
    const bool b1 = d < d1;
    const bool b2 = d < d2;
    i2 = b1 ? i1 : (b2 ? s : i2);   // reads old i1
    i1 = b0 ? i0 : (b1 ? s : i1);   // reads old i0
    i0 = b0 ? s  : i0;
    const float nd1 = __builtin_amdgcn_fmed3f(d, d0, d1);  // new d1
    d2 = __builtin_amdgcn_fmed3f(d, d1, d2);               // uses old d1
    d0 = fminf(d, d0);
    d1 = nd1;
}

// ---------------------------------------------------------------------------
// Single-pass KNN tile: 256 threads = 32 queries x 8 candidate-splits.
// All S candidates staged once in LDS (float4: x,y,z,|p|^2). Each thread
// scans S/8 candidates; 8 split top-3 lists merged in LDS in ascending split
// order (tie order == full ascending scan). Writes idx/w directly.
// ---------------------------------------------------------------------------
template <int S>
__device__ void knn_tile(const float* __restrict__ xyzF, const float* __restrict__ xyzC,
                         int N, int b, int nb,
                         int* __restrict__ idx, float* __restrict__ w,
                         void* smem) {
    constexpr int SPC = S / 8;
    float4* sc  = (float4*)smem;                       // S * 16 B
    float*  smd = (float*)((char*)smem + S * 16);      // [256][3] floats
    int*    smi = (int*)((char*)smem + S * 16 + 3072); // [256][3] ints
    const int tid = threadIdx.x;

    for (int i = tid; i < S; i += 256) {
        const float x = xyzC[(b * S + i) * 3 + 0];
        const float y = xyzC[(b * S + i) * 3 + 1];
        const float z = xyzC[(b * S + i) * 3 + 2];
        sc[i] = make_float4(x, y, z, x * x + y * y + z * z);
    }
    __syncthreads();

    const int q  = tid & 31;          // query within tile
    const int sp = tid >> 5;          // candidate split 0..7
    const int n  = nb + q;
    const float ax = xyzF[(b * N + n) * 3 + 0];
    const float ay = xyzF[(b * N + n) * 3 + 1];
    const float az = xyzF[(b * N + n) * 3 + 2];
    const float an = ax * ax + ay * ay + az * az;

    float d0 = BIG, d1 = BIG, d2 = BIG;
    int i0 = 0, i1 = 0, i2 = 0;
    const int s0 = sp * SPC;
#pragma unroll 8
    for (int s = s0; s < s0 + SPC; ++s) {
        const float4 p = sc[s];       // 2 distinct addrs per wave -> ~free
        const float t = ax * p.x + ay * p.y + az * p.z;
        const float d = an + p.w - 2.0f * t;   // matches ref formula exactly
        insert3(d, s, d0, d1, d2, i0, i1, i2);
    }

    smd[tid * 3 + 0] = d0; smi[tid * 3 + 0] = i0;
    smd[tid * 3 + 1] = d1; smi[tid * 3 + 1] = i1;
    smd[tid * 3 + 2] = d2; smi[tid * 3 + 2] = i2;
    __syncthreads();

    if (tid < 32) {                   // one thread per query merges 8 splits
        float e0 = BIG, e1 = BIG, e2 = BIG;
        int j0 = 0, j1 = 0, j2 = 0;
#pragma unroll
        for (int ch = 0; ch < 8; ++ch) {
#pragma unroll
            for (int k = 0; k < 3; ++k) {
                insert3(smd[(ch * 32 + tid) * 3 + k], smi[(ch * 32 + tid) * 3 + k],
                        e0, e1, e2, j0, j1, j2);
            }
        }
        const float r0 = 1.0f / (e0 + 1e-8f);
        const float r1 = 1.0f / (e1 + 1e-8f);
        const float r2 = 1.0f / (e2 + 1e-8f);
        const float rs = r0 + r1 + r2;
        const int nn = nb + tid;
        idx[(b * 3 + 0) * N + nn] = j0;
        idx[(b * 3 + 1) * N + nn] = j1;
        idx[(b * 3 + 2) * N + nn] = j2;
        w[(b * 3 + 0) * N + nn] = r0 / rs;
        w[(b * 3 + 1) * N + nn] = r1 / rs;
        w[(b * 3 + 2) * N + nn] = r2 / rs;
    }
}

// ---------------------------------------------------------------------------
// 64x64 tile transpose [B,C,N] -> point-major out[b][n][c] (row stride OS).
// ---------------------------------------------------------------------------
__device__ void transpose_tile(const float* __restrict__ in, float* __restrict__ out,
                               int C, int N, int OS,
                               int b, int nb, int cb, void* smem) {
    float (*s)[65] = (float (*)[65])smem;
    const int lo = threadIdx.x & 63;
    const int r  = threadIdx.x >> 6;
#pragma unroll
    for (int i = 0; i < 16; ++i) {
        const int cl = r + 4 * i;
        s[cl][lo] = in[((size_t)b * C + cb + cl) * N + nb + lo];
    }
    __syncthreads();
#pragma unroll
    for (int i = 0; i < 16; ++i) {
        const int pl = r + 4 * i;
        out[((size_t)b * N + nb + pl) * OS + cb + lo] = s[lo][pl];
    }
}

// ---------------------------------------------------------------------------
// K1: all mutually-independent prep work, block ranges (R3 form, known-good).
//   [   0,1024)  knn2: xyz0 vs xyz1 -> idx2/w2
//   [1024,1280)  knn1: xyz1 vs xyz2 -> idx1/w1
//   [1280,1536)  t_x2: x2 -> x2P [B][512][512]
//   [1536,2048)  t_x1: x1 -> x1P [B][2048][256]
//   [2048,2304)  copy x0 -> out channels 0..127 (NT stream)
// ---------------------------------------------------------------------------
__global__ __launch_bounds__(256) void k1_stage(const float* __restrict__ xyz0,
                                                const float* __restrict__ xyz1,
                                                const float* __restrict__ xyz2,
                                                const float* __restrict__ x0,
                                                const float* __restrict__ x1,
                                                const float* __restrict__ x2,
                                                float* __restrict__ x1P,
                                                float* __restrict__ x2P,
                                                int* __restrict__ idx1,
                                                float* __restrict__ w1,
                                                int* __restrict__ idx2,
                                                float* __restrict__ w2,
                                                float* __restrict__ out) {
    __shared__ float4 smem4[2432];   // 38,912 B union: knn2 38,912 / transpose 16,640
    const int id = blockIdx.x;
    if (id < 1024) {
        const int b  = id >> 8;
        const int nb = (id & 255) * 32;
        knn_tile<2048>(xyz0, xyz1, 8192, b, nb, idx2, w2, smem4);
    } else if (id < 1280) {
        const int r  = id - 1024;
        const int b  = r >> 6;
        const int nb = (r & 63) * 32;
        knn_tile<512>(xyz1, xyz2, 2048, b, nb, idx1, w1, smem4);
    } else if (id < 1536) {
        const int r  = id - 1280;
        const int b  = r >> 6;
        const int nb = (r & 7) * 64;
        const int cb = ((r >> 3) & 7) * 64;
        transpose_tile(x2, x2P, 512, 512, 512, b, nb, cb, smem4);
    } else if (id < 2048) {
        const int r  = id - 1536;
        const int b  = r >> 7;
        const int nb = (r & 31) * 64;
        const int cb = ((r >> 5) & 3) * 64;
        transpose_tile(x1, x1P, 256, 2048, 256, b, nb, cb, smem4);
    } else {
        const int r  = id - 2048;          // 0..255
        const int b  = r >> 6;
        const int lb = r & 63;
        const vf4* src = (const vf4*)x0;
        vf4* dst = (vf4*)out;
#pragma unroll
        for (int t = 0; t < 16; ++t) {
            const int i = lb * 4096 + t * 256 + threadIdx.x;   // 0..262143
            const vf4 v = __builtin_nontemporal_load(&src[(size_t)b * (128 * 2048) + i]);
            __builtin_nontemporal_store(v, &dst[(size_t)b * (896 * 2048) + i]);
        }
    }
}

// ---------------------------------------------------------------------------
// K2: one block per (batch, n-tile of 64 points) = 512 blocks; each block
// composes its 9-neighbor (offset, weight) table ONCE (was 8x per point in
// R3, 16x in R6), then serves ALL 12 channel-tiles: 4 x 3-gather of x1P
// (ch 128..383) + 8 x 9-gather of x2P (ch 384..895). Gathers stay in L2
// (structure A: lane = channel, wave-uniform row -> 256 B coalesced reads).
// Indices stored as pre-multiplied element offsets (row*OS) -> gather is
// saddr+voffset, no per-read multiply. Batch pinned to an XCD pair
// (per-XCD hot set = x1P 2MB + x2P 1MB < 4MB L2); NT stores keep the
// 100 MB write stream from evicting it. 22.8 KB LDS -> all 512 blocks
// co-resident (2/CU), single generation.
// ---------------------------------------------------------------------------
__global__ __launch_bounds__(256) void final_unified(const float* __restrict__ x1P,
                                                     const float* __restrict__ x2P,
                                                     const int* __restrict__ idx1,
                                                     const float* __restrict__ w1,
                                                     const int* __restrict__ idx2,
                                                     const float* __restrict__ w2,
                                                     float* __restrict__ out) {
    __shared__ float tile[64][65];
    __shared__ int   sj1[3][64];
    __shared__ float sw1[3][64];
    __shared__ int   sj9[9][64];
    __shared__ float sw9[9][64];
    const int id  = blockIdx.x;               // 0..511
    const int xcd = id & 7;
    const int b   = xcd >> 1;                 // batch -> XCD pair
    const int ntile = ((id >> 3) << 1) | (xcd & 1);   // 0..127, bijective
    const int nb  = ntile * 64;
    const int tid = threadIdx.x;

    // ---- setup: compose per-point tables once (192 threads = 3k x 64p) ----
    if (tid < 192) {
        const int p = tid & 63, k = tid >> 6;
        const int   j  = idx2[(b * 3 + k) * 8192 + nb + p];
        const float wk = w2[(b * 3 + k) * 8192 + nb + p];
        sj1[k][p] = j * 256;                  // element offset into x1P
        sw1[k][p] = wk;
#pragma unroll
        for (int m = 0; m < 3; ++m) {
            sj9[k * 3 + m][p] = idx1[(b * 3 + m) * 2048 + j] * 512;  // offset into x2P
            sw9[k * 3 + m][p] = wk * w1[(b * 3 + m) * 2048 + j];
        }
    }
    __syncthreads();

    const int c = tid & 63;    // lane = channel in gather phase
    const int r = tid >> 6;

    // ---- x1 part: 4 ctiles -> out channels 128..383 ----
    for (int ct = 0; ct < 4; ++ct) {
        const int cb = ct * 64;
        const float* xb = x1P + (size_t)b * 2048 * 256 + cb + c;
#pragma unroll 8
        for (int i = 0; i < 16; ++i) {
            const int p = r + 4 * i;
            tile[p][c] = sw1[0][p] * xb[sj1[0][p]]
                       + sw1[1][p] * xb[sj1[1][p]]
                       + sw1[2][p] * xb[sj1[2][p]];
        }
        __syncthreads();
        {
            const int p = tid & 63;   // lane = point in write phase
#pragma unroll
            for (int i = 0; i < 16; ++i) {
                const int cl = r + 4 * i;
                __builtin_nontemporal_store(tile[p][cl],
                    &out[((size_t)b * 896 + 128 + cb + cl) * 8192 + nb + p]);
            }
        }
        __syncthreads();
    }

    // ---- x2 part: 8 ctiles -> out channels 384..895 (composed 9-gather) ----
    for (int ct = 0; ct < 8; ++ct) {
        const int cb = ct * 64;
        const float* xb = x2P + (size_t)b * 512 * 512 + cb + c;
#pragma unroll 4
        for (int i = 0; i < 16; ++i) {
            const int p = r + 4 * i;
            float v = 0.0f;
#pragma unroll
            for (int j = 0; j < 9; ++j) {
                v += sw9[j][p] * xb[sj9[j][p]];
            }
            tile[p][c] = v;
        }
        __syncthreads();
        {
            const int p = tid & 63;
#pragma unroll
            for (int i = 0; i < 16; ++i) {
                const int cl = r + 4 * i;
                __builtin_nontemporal_store(tile[p][cl],
                    &out[((size_t)b * 896 + 384 + cb + cl) * 8192 + nb + p]);
            }
        }
        __syncthreads();
    }
}

extern "C" void kernel_launch(void* const* d_in, const int* in_sizes, int n_in,
                              void* d_out, int out_size, void* d_ws, size_t ws_size,
                              hipStream_t stream) {
    const float* xyz0 = (const float*)d_in[0];  // [4,8192,3]
    const float* xyz1 = (const float*)d_in[1];  // [4,2048,3]
    const float* xyz2 = (const float*)d_in[2];  // [4,512,3]
    const float* x0   = (const float*)d_in[3];  // [4,128,8192]
    const float* x1   = (const float*)d_in[4];  // [4,256,2048]
    const float* x2   = (const float*)d_in[5];  // [4,512,512]
    float* out = (float*)d_out;                 // [4,896,8192]

    // Workspace layout (bytes), total 13,565,952:
    //   x1P   : float[4*2048*256] @ 0          (8,388,608)  point-major x1
    //   x2P   : float[4*512*512]  @ 8,388,608  (4,194,304)  point-major x2
    //   idx1  : int  [4*3*2048]   @ 12,582,912 (98,304)
    //   w1    : float[4*3*2048]   @ 12,681,216 (98,304)
    //   idx2  : int  [4*3*8192]   @ 12,779,520 (393,216)
    //   w2    : float[4*3*8192]   @ 13,172,736 (393,216)
    char* ws = (char*)d_ws;
    float* x1P  = (float*)(ws + 0);
    float* x2P  = (float*)(ws + 8388608);
    int*   idx1 = (int*)(ws + 12582912);
    float* w1   = (float*)(ws + 12681216);
    int*   idx2 = (int*)(ws + 12779520);
    float* w2   = (float*)(ws + 13172736);

    // K1: both KNNs + both point-major transposes + x0 copy.
    k1_stage<<<dim3(2304), 256, 0, stream>>>(xyz0, xyz1, xyz2, x0, x1, x2,
                                             x1P, x2P, idx1, w1, idx2, w2, out);
    // K2: all interpolated output channels, composition amortized per n-tile.
    final_unified<<<dim3(512), 256, 0, stream>>>(x1P, x2P, idx1, w1, idx2, w2, out);
}

// Round 8
// 204.440 us; speedup vs baseline: 1.2176x; 1.2176x over previous
//
#include <hip/hip_runtime.h>

#define BIG 3.0e38f

typedef float vf4 __attribute__((ext_vector_type(4)));

__device__ __forceinline__ vf4 ld4(const float* p) { return *(const vf4*)p; }

// ---------------------------------------------------------------------------
// Branchless top-3 insert (strict <). Distances via fmin/med3 (values), index
// chain via csel off 3 compares. Used in the scan where visit order is
// ascending-index, so strict < == lowest-index tie rule.
// ---------------------------------------------------------------------------
__device__ __forceinline__ void insert3(float d, int s,
                                        float& d0, float& d1, float& d2,
                                        int& i0, int& i1, int& i2) {
    const bool b0 = d < d0;
    const bool b1 = d < d1;
    const bool b2 = d < d2;
    i2 = b1 ? i1 : (b2 ? s : i2);   // reads old i1
    i1 = b0 ? i0 : (b1 ? s : i1);   // reads old i0
    i0 = b0 ? s  : i0;
    const float nd1 = __builtin_amdgcn_fmed3f(d, d0, d1);  // new d1
    d2 = __builtin_amdgcn_fmed3f(d, d1, d2);               // uses old d1
    d0 = fminf(d, d0);
    d1 = nd1;
}

// Tie-aware variant for the merge phase: lexicographic (d, index) so the
// global lowest-index-on-tie rule holds even when split ranges interleave
// (2-phase staging makes per-split candidate sets non-contiguous).
__device__ __forceinline__ void insert3_tie(float d, int s,
                                            float& d0, float& d1, float& d2,
                                            int& i0, int& i1, int& i2) {
    const bool b0 = (d < d0) | ((d == d0) & (s < i0));
    const bool b1 = (d < d1) | ((d == d1) & (s < i1));
    const bool b2 = (d < d2) | ((d == d2) & (s < i2));
    i2 = b1 ? i1 : (b2 ? s : i2);
    i1 = b0 ? i0 : (b1 ? s : i1);
    i0 = b0 ? s  : i0;
    d2 = b1 ? d1 : (b2 ? d : d2);
    d1 = b0 ? d0 : (b1 ? d : d1);
    d0 = b0 ? d  : d0;
}

// ---------------------------------------------------------------------------
// KNN tile: 256 threads = 32 queries x 8 splits, PHASES-way candidate
// staging (PHASES=2 halves LDS for knn2: 38.9 -> 22.5 KB => 7 blocks/CU).
// Scan uses monotone surrogate h = 0.5|p|^2 - a.p (3 fma); true
// d = 2h + |a|^2 recovered at merge for weights.
// ---------------------------------------------------------------------------
template <int S, int PHASES>
__device__ void knn_tile(const float* __restrict__ xyzF, const float* __restrict__ xyzC,
                         int N, int b, int nb,
                         int* __restrict__ idx, float* __restrict__ w,
                         void* smem) {
    constexpr int H   = S / PHASES;    // candidates per phase
    constexpr int SPC = H / 8;         // per-thread per-phase
    float4* sc  = (float4*)smem;                        // H * 16 B
    float*  smd = (float*)((char*)smem + H * 16);       // [256][3]
    int*    smi = (int*)((char*)smem + H * 16 + 3072);  // [256][3]
    const int tid = threadIdx.x;
    const int q   = tid & 31;
    const int sp  = tid >> 5;
    const int n   = nb + q;
    const float ax = xyzF[(b * N + n) * 3 + 0];
    const float ay = xyzF[(b * N + n) * 3 + 1];
    const float az = xyzF[(b * N + n) * 3 + 2];

    float d0 = BIG, d1 = BIG, d2 = BIG;
    int i0 = 0, i1 = 0, i2 = 0;

    for (int ph = 0; ph < PHASES; ++ph) {
        const int base = ph * H;
        if (ph) __syncthreads();       // previous scan done before restage
        for (int i = tid; i < H; i += 256) {
            const float x = xyzC[(b * S + base + i) * 3 + 0];
            const float y = xyzC[(b * S + base + i) * 3 + 1];
            const float z = xyzC[(b * S + base + i) * 3 + 2];
            sc[i] = make_float4(x, y, z, 0.5f * (x * x + y * y + z * z));
        }
        __syncthreads();
        const int s0 = sp * SPC;
#pragma unroll 8
        for (int t = 0; t < SPC; ++t) {
            const float4 p = sc[s0 + t];   // 2 distinct addrs/wave -> ~free
            const float h = fmaf(-ax, p.x, fmaf(-ay, p.y, fmaf(-az, p.z, p.w)));
            insert3(h, base + s0 + t, d0, d1, d2, i0, i1, i2);
        }
    }

    smd[tid * 3 + 0] = d0; smi[tid * 3 + 0] = i0;
    smd[tid * 3 + 1] = d1; smi[tid * 3 + 1] = i1;
    smd[tid * 3 + 2] = d2; smi[tid * 3 + 2] = i2;
    __syncthreads();

    if (tid < 32) {                    // one thread per query merges 8 splits
        float e0 = BIG, e1 = BIG, e2 = BIG;
        int j0 = 0, j1 = 0, j2 = 0;
#pragma unroll
        for (int ch = 0; ch < 8; ++ch) {
#pragma unroll
            for (int k = 0; k < 3; ++k) {
                insert3_tie(smd[(ch * 32 + tid) * 3 + k], smi[(ch * 32 + tid) * 3 + k],
                            e0, e1, e2, j0, j1, j2);
            }
        }
        const float an = ax * ax + ay * ay + az * az;  // tid<32 owns query tid
        const float r0 = 1.0f / (fmaf(2.0f, e0, an) + 1e-8f);
        const float r1 = 1.0f / (fmaf(2.0f, e1, an) + 1e-8f);
        const float r2 = 1.0f / (fmaf(2.0f, e2, an) + 1e-8f);
        const float rs = r0 + r1 + r2;
        const int nn = nb + tid;
        idx[(b * 3 + 0) * N + nn] = j0;
        idx[(b * 3 + 1) * N + nn] = j1;
        idx[(b * 3 + 2) * N + nn] = j2;
        w[(b * 3 + 0) * N + nn] = r0 / rs;
        w[(b * 3 + 1) * N + nn] = r1 / rs;
        w[(b * 3 + 2) * N + nn] = r2 / rs;
    }
}

// ---------------------------------------------------------------------------
// 64x64 tile transpose [B,C,N] -> point-major out[b][n][c] (row stride OS).
// ---------------------------------------------------------------------------
__device__ void transpose_tile(const float* __restrict__ in, float* __restrict__ out,
                               int C, int N, int OS,
                               int b, int nb, int cb, void* smem) {
    float (*s)[65] = (float (*)[65])smem;
    const int lo = threadIdx.x & 63;
    const int r  = threadIdx.x >> 6;
#pragma unroll
    for (int i = 0; i < 16; ++i) {
        const int cl = r + 4 * i;
        s[cl][lo] = in[((size_t)b * C + cb + cl) * N + nb + lo];
    }
    __syncthreads();
#pragma unroll
    for (int i = 0; i < 16; ++i) {
        const int pl = r + 4 * i;
        out[((size_t)b * N + nb + pl) * OS + cb + lo] = s[lo][pl];
    }
}

// ---------------------------------------------------------------------------
// K1: KNNs + transposes (copy_x0 moved to K2 -- it has no dependents there).
// LDS union now 22.5 KB (2-phase knn2) => 7 blocks/CU for every block type.
//   [   0,1024)  knn2: xyz0 vs xyz1 -> idx2/w2   (2-phase staging)
//   [1024,1280)  knn1: xyz1 vs xyz2 -> idx1/w1
//   [1280,1536)  t_x2: x2 -> x2P [B][512][512]
//   [1536,2048)  t_x1: x1 -> x1P [B][2048][256]
// ---------------------------------------------------------------------------
__global__ __launch_bounds__(256) void k1_stage(const float* __restrict__ xyz0,
                                                const float* __restrict__ xyz1,
                                                const float* __restrict__ xyz2,
                                                const float* __restrict__ x1,
                                                const float* __restrict__ x2,
                                                float* __restrict__ x1P,
                                                float* __restrict__ x2P,
                                                int* __restrict__ idx1,
                                                float* __restrict__ w1,
                                                int* __restrict__ idx2,
                                                float* __restrict__ w2) {
    __shared__ float4 smem4[1408];   // 22,528 B union
    const int id = blockIdx.x;
    if (id < 1024) {
        const int b  = id >> 8;
        const int nb = (id & 255) * 32;
        knn_tile<2048, 2>(xyz0, xyz1, 8192, b, nb, idx2, w2, smem4);
    } else if (id < 1280) {
        const int r  = id - 1024;
        const int b  = r >> 6;
        const int nb = (r & 63) * 32;
        knn_tile<512, 1>(xyz1, xyz2, 2048, b, nb, idx1, w1, smem4);
    } else if (id < 1536) {
        const int r  = id - 1280;
        const int b  = r >> 6;
        const int nb = (r & 7) * 64;
        const int cb = ((r >> 3) & 7) * 64;
        transpose_tile(x2, x2P, 512, 512, 512, b, nb, cb, smem4);
    } else {
        const int r  = id - 1536;
        const int b  = r >> 7;
        const int nb = (r & 31) * 64;
        const int cb = ((r >> 5) & 3) * 64;
        transpose_tile(x1, x1P, 256, 2048, 256, b, nb, cb, smem4);
    }
}

// ---------------------------------------------------------------------------
// K2: all output work, one dispatch, high occupancy (~22 KB LDS, 7 blk/CU).
// Gathers use lane=(channel-quad, point-group): one dwordx4 instr covers
// 4 points x 16B = 1 KB (4x fewer VMEM instrs than lane=channel scalar).
//   [   0,1024)  x2 part: (b, ntile, ctile-quad) -> out ch 384..895
//                9-gather of x2P, composed weights; compose once per block.
//   [1024,3072)  x1 part: (b, ntile, ctile) -> out ch 128..383, 3-gather.
//   [3072,3328)  copy x0 -> out ch 0..127 (NT stream, overlaps gather lat.)
// ---------------------------------------------------------------------------
__global__ __launch_bounds__(256) void k2_final(const float* __restrict__ x0,
                                                const float* __restrict__ x1P,
                                                const float* __restrict__ x2P,
                                                const int* __restrict__ idx1,
                                                const float* __restrict__ w1,
                                                const int* __restrict__ idx2,
                                                const float* __restrict__ w2,
                                                float* __restrict__ out) {
    __shared__ vf4 smemv[1376];                  // 22,016 B
    float (*tile)[68] = (float (*)[68])smemv;    // [64][68] floats (rows 16B-aligned)
    int*   sj9 = (int*)((float*)smemv + 4352);   // [9][64]
    float* sw9 = (float*)((float*)smemv + 4928); // [9][64]
    const int id  = blockIdx.x;
    const int tid = threadIdx.x;
    const int q4  = tid & 15;          // channel quad (4 ch)
    const int pg  = (tid >> 4) & 3;    // point sub-group
    const int r   = tid >> 6;          // wave

    if (id < 1024) {
        // ---------------- x2 part: 9-gather, composed weights ----------------
        const int b     = id >> 8;
        const int rem   = id & 255;
        const int ntile = rem >> 1;
        const int cq    = rem & 1;     // ctiles cq*4 .. cq*4+3
        const int nb    = ntile * 64;

        if (tid < 192) {               // compose once per block (3k x 64p)
            const int p = tid & 63, k = tid >> 6;
            const int   j  = idx2[(b * 3 + k) * 8192 + nb + p];
            const float wk = w2[(b * 3 + k) * 8192 + nb + p];
#pragma unroll
            for (int m = 0; m < 3; ++m) {
                sj9[(k * 3 + m) * 64 + p] = idx1[(b * 3 + m) * 2048 + j] * 512;
                sw9[(k * 3 + m) * 64 + p] = wk * w1[(b * 3 + m) * 2048 + j];
            }
        }
        __syncthreads();

        for (int ct = 0; ct < 4; ++ct) {
            const int cb = (cq * 4 + ct) * 64;
            const float* xb = x2P + (size_t)b * 512 * 512 + cb + q4 * 4;
#pragma unroll
            for (int i = 0; i < 4; ++i) {
                const int p = i * 16 + r * 4 + pg;
                vf4 acc = sw9[0 * 64 + p] * ld4(xb + sj9[0 * 64 + p]);
#pragma unroll
                for (int j = 1; j < 9; ++j) {
                    acc += sw9[j * 64 + p] * ld4(xb + sj9[j * 64 + p]);
                }
                *(vf4*)&tile[p][q4 * 4] = acc;
            }
            __syncthreads();
            {
                const int p2 = tid & 63;
#pragma unroll
                for (int i = 0; i < 16; ++i) {
                    const int cl = r + 4 * i;
                    __builtin_nontemporal_store(tile[p2][cl],
                        &out[((size_t)b * 896 + 384 + cb + cl) * 8192 + nb + p2]);
                }
            }
            __syncthreads();
        }
    } else if (id < 3072) {
        // ---------------- x1 part: 3-gather with w2 ----------------
        const int t     = id - 1024;
        const int b     = t >> 9;
        const int rem   = t & 511;
        const int ntile = rem >> 2;
        const int ct    = rem & 3;
        const int nb    = ntile * 64;
        const int cb    = ct * 64;
        int*   sj1 = sj9;              // alias (first 3 rows)
        float* sw1 = sw9;

        if (tid < 192) {
            const int p = tid & 63, k = tid >> 6;
            sj1[k * 64 + p] = idx2[(b * 3 + k) * 8192 + nb + p] * 256;
            sw1[k * 64 + p] = w2[(b * 3 + k) * 8192 + nb + p];
        }
        __syncthreads();

        const float* xb = x1P + (size_t)b * 2048 * 256 + cb + q4 * 4;
#pragma unroll
        for (int i = 0; i < 4; ++i) {
            const int p = i * 16 + r * 4 + pg;
            const vf4 acc = sw1[0 * 64 + p] * ld4(xb + sj1[0 * 64 + p])
                          + sw1[1 * 64 + p] * ld4(xb + sj1[1 * 64 + p])
                          + sw1[2 * 64 + p] * ld4(xb + sj1[2 * 64 + p]);
            *(vf4*)&tile[p][q4 * 4] = acc;
        }
        __syncthreads();
        {
            const int p2 = tid & 63;
#pragma unroll
            for (int i = 0; i < 16; ++i) {
                const int cl = r + 4 * i;
                __builtin_nontemporal_store(tile[p2][cl],
                    &out[((size_t)b * 896 + 128 + cb + cl) * 8192 + nb + p2]);
            }
        }
    } else {
        // ---------------- copy x0 -> out channels 0..127 ----------------
        const int rr = id - 3072;          // 0..255
        const int b  = rr >> 6;
        const int lb = rr & 63;
        const vf4* src = (const vf4*)x0;
        vf4* dst = (vf4*)out;
#pragma unroll
        for (int t2 = 0; t2 < 16; ++t2) {
            const int i = lb * 4096 + t2 * 256 + tid;    // 0..262143
            const vf4 v = __builtin_nontemporal_load(&src[(size_t)b * (128 * 2048) + i]);
            __builtin_nontemporal_store(v, &dst[(size_t)b * (896 * 2048) + i]);
        }
    }
}

extern "C" void kernel_launch(void* const* d_in, const int* in_sizes, int n_in,
                              void* d_out, int out_size, void* d_ws, size_t ws_size,
                              hipStream_t stream) {
    const float* xyz0 = (const float*)d_in[0];  // [4,8192,3]
    const float* xyz1 = (const float*)d_in[1];  // [4,2048,3]
    const float* xyz2 = (const float*)d_in[2];  // [4,512,3]
    const float* x0   = (const float*)d_in[3];  // [4,128,8192]
    const float* x1   = (const float*)d_in[4];  // [4,256,2048]
    const float* x2   = (const float*)d_in[5];  // [4,512,512]
    float* out = (float*)d_out;                 // [4,896,8192]

    // Workspace layout (bytes), total 13,565,952:
    //   x1P   : float[4*2048*256] @ 0          (8,388,608)  point-major x1
    //   x2P   : float[4*512*512]  @ 8,388,608  (4,194,304)  point-major x2
    //   idx1  : int  [4*3*2048]   @ 12,582,912 (98,304)
    //   w1    : float[4*3*2048]   @ 12,681,216 (98,304)
    //   idx2  : int  [4*3*8192]   @ 12,779,520 (393,216)
    //   w2    : float[4*3*8192]   @ 13,172,736 (393,216)
    char* ws = (char*)d_ws;
    float* x1P  = (float*)(ws + 0);
    float* x2P  = (float*)(ws + 8388608);
    int*   idx1 = (int*)(ws + 12582912);
    float* w1   = (float*)(ws + 12681216);
    int*   idx2 = (int*)(ws + 12779520);
    float* w2   = (float*)(ws + 13172736);

    // K1: both KNNs + both point-major transposes (7 blocks/CU).
    k1_stage<<<dim3(2048), 256, 0, stream>>>(xyz0, xyz1, xyz2, x1, x2,
                                             x1P, x2P, idx1, w1, idx2, w2);
    // K2: all output channels + x0 copy, one high-occupancy dispatch.
    k2_final<<<dim3(3328), 256, 0, stream>>>(x0, x1P, x2P, idx1, w1, idx2, w2, out);
}

// Round 10
// 200.498 us; speedup vs baseline: 1.2416x; 1.0197x over previous
//
#include <hip/hip_runtime.h>

#define BIG 3.0e38f

typedef float vf4 __attribute__((ext_vector_type(4)));

__device__ __forceinline__ vf4 ld4(const float* p) { return *(const vf4*)p; }

// ---------------------------------------------------------------------------
// Branchless top-3 insert (strict <). Distances via fmin/med3 (values), index
// chain via csel off 3 compares. Used in the scan where visit order is
// ascending-index, so strict < == lowest-index tie rule.
// ---------------------------------------------------------------------------
__device__ __forceinline__ void insert3(float d, int s,
                                        float& d0, float& d1, float& d2,
                                        int& i0, int& i1, int& i2) {
    const bool b0 = d < d0;
    const bool b1 = d < d1;
    const bool b2 = d < d2;
    i2 = b1 ? i1 : (b2 ? s : i2);   // reads old i1
    i1 = b0 ? i0 : (b1 ? s : i1);   // reads old i0
    i0 = b0 ? s  : i0;
    const float nd1 = __builtin_amdgcn_fmed3f(d, d0, d1);  // new d1
    d2 = __builtin_amdgcn_fmed3f(d, d1, d2);               // uses old d1
    d0 = fminf(d, d0);
    d1 = nd1;
}

// Tie-aware variant for the merge phase: lexicographic (d, index) so the
// global lowest-index-on-tie rule holds even when split ranges interleave
// (2-phase staging makes per-split candidate sets non-contiguous).
__device__ __forceinline__ void insert3_tie(float d, int s,
                                            float& d0, float& d1, float& d2,
                                            int& i0, int& i1, int& i2) {
    const bool b0 = (d < d0) | ((d == d0) & (s < i0));
    const bool b1 = (d < d1) | ((d == d1) & (s < i1));
    const bool b2 = (d < d2) | ((d == d2) & (s < i2));
    i2 = b1 ? i1 : (b2 ? s : i2);
    i1 = b0 ? i0 : (b1 ? s : i1);
    i0 = b0 ? s  : i0;
    d2 = b1 ? d1 : (b2 ? d : d2);
    d1 = b0 ? d0 : (b1 ? d : d1);
    d0 = b0 ? d  : d0;
}

// ---------------------------------------------------------------------------
// KNN tile: 256 threads = 32 queries x 8 splits, PHASES-way candidate
// staging (PHASES=2 halves LDS for knn2: 38.9 -> 22.5 KB => 7 blocks/CU).
// Scan uses monotone surrogate h = 0.5|p|^2 - a.p (3 fma); true
// d = 2h + |a|^2 recovered at merge for weights. (unchanged from R8)
// ---------------------------------------------------------------------------
template <int S, int PHASES>
__device__ void knn_tile(const float* __restrict__ xyzF, const float* __restrict__ xyzC,
                         int N, int b, int nb,
                         int* __restrict__ idx, float* __restrict__ w,
                         void* smem) {
    constexpr int H   = S / PHASES;    // candidates per phase
    constexpr int SPC = H / 8;         // per-thread per-phase
    float4* sc  = (float4*)smem;                        // H * 16 B
    float*  smd = (float*)((char*)smem + H * 16);       // [256][3]
    int*    smi = (int*)((char*)smem + H * 16 + 3072);  // [256][3]
    const int tid = threadIdx.x;
    const int q   = tid & 31;
    const int sp  = tid >> 5;
    const int n   = nb + q;
    const float ax = xyzF[(b * N + n) * 3 + 0];
    const float ay = xyzF[(b * N + n) * 3 + 1];
    const float az = xyzF[(b * N + n) * 3 + 2];

    float d0 = BIG, d1 = BIG, d2 = BIG;
    int i0 = 0, i1 = 0, i2 = 0;

    for (int ph = 0; ph < PHASES; ++ph) {
        const int base = ph * H;
        if (ph) __syncthreads();       // previous scan done before restage
        for (int i = tid; i < H; i += 256) {
            const float x = xyzC[(b * S + base + i) * 3 + 0];
            const float y = xyzC[(b * S + base + i) * 3 + 1];
            const float z = xyzC[(b * S + base + i) * 3 + 2];
            sc[i] = make_float4(x, y, z, 0.5f * (x * x + y * y + z * z));
        }
        __syncthreads();
        const int s0 = sp * SPC;
#pragma unroll 8
        for (int t = 0; t < SPC; ++t) {
            const float4 p = sc[s0 + t];   // 2 distinct addrs/wave -> ~free
            const float h = fmaf(-ax, p.x, fmaf(-ay, p.y, fmaf(-az, p.z, p.w)));
            insert3(h, base + s0 + t, d0, d1, d2, i0, i1, i2);
        }
    }

    smd[tid * 3 + 0] = d0; smi[tid * 3 + 0] = i0;
    smd[tid * 3 + 1] = d1; smi[tid * 3 + 1] = i1;
    smd[tid * 3 + 2] = d2; smi[tid * 3 + 2] = i2;
    __syncthreads();

    if (tid < 32) {                    // one thread per query merges 8 splits
        float e0 = BIG, e1 = BIG, e2 = BIG;
        int j0 = 0, j1 = 0, j2 = 0;
#pragma unroll
        for (int ch = 0; ch < 8; ++ch) {
#pragma unroll
            for (int k = 0; k < 3; ++k) {
                insert3_tie(smd[(ch * 32 + tid) * 3 + k], smi[(ch * 32 + tid) * 3 + k],
                            e0, e1, e2, j0, j1, j2);
            }
        }
        const float an = ax * ax + ay * ay + az * az;  // tid<32 owns query tid
        const float r0 = 1.0f / (fmaf(2.0f, e0, an) + 1e-8f);
        const float r1 = 1.0f / (fmaf(2.0f, e1, an) + 1e-8f);
        const float r2 = 1.0f / (fmaf(2.0f, e2, an) + 1e-8f);
        const float rs = r0 + r1 + r2;
        const int nn = nb + tid;
        idx[(b * 3 + 0) * N + nn] = j0;
        idx[(b * 3 + 1) * N + nn] = j1;
        idx[(b * 3 + 2) * N + nn] = j2;
        w[(b * 3 + 0) * N + nn] = r0 / rs;
        w[(b * 3 + 1) * N + nn] = r1 / rs;
        w[(b * 3 + 2) * N + nn] = r2 / rs;
    }
}

// ---------------------------------------------------------------------------
// 64x64 tile transpose [B,C,N] -> point-major out[b][n][c] (row stride OS).
// ---------------------------------------------------------------------------
__device__ void transpose_tile(const float* __restrict__ in, float* __restrict__ out,
                               int C, int N, int OS,
                               int b, int nb, int cb, void* smem) {
    float (*s)[65] = (float (*)[65])smem;
    const int lo = threadIdx.x & 63;
    const int r  = threadIdx.x >> 6;
#pragma unroll
    for (int i = 0; i < 16; ++i) {
        const int cl = r + 4 * i;
        s[cl][lo] = in[((size_t)b * C + cb + cl) * N + nb + lo];
    }
    __syncthreads();
#pragma unroll
    for (int i = 0; i < 16; ++i) {
        const int pl = r + 4 * i;
        out[((size_t)b * N + nb + pl) * OS + cb + lo] = s[lo][pl];
    }
}

// ---------------------------------------------------------------------------
// K1: KNNs + transposes -- byte-identical to R8.
//   [   0,1024)  knn2: xyz0 vs xyz1 -> idx2/w2   (2-phase staging)
//   [1024,1280)  knn1: xyz1 vs xyz2 -> idx1/w1
//   [1280,1536)  t_x2: x2 -> x2P [B][512][512]
//   [1536,2048)  t_x1: x1 -> x1P [B][2048][256]
// ---------------------------------------------------------------------------
__global__ __launch_bounds__(256) void k1_stage(const float* __restrict__ xyz0,
                                                const float* __restrict__ xyz1,
                                                const float* __restrict__ xyz2,
                                                const float* __restrict__ x1,
                                                const float* __restrict__ x2,
                                                float* __restrict__ x1P,
                                                float* __restrict__ x2P,
                                                int* __restrict__ idx1,
                                                float* __restrict__ w1,
                                                int* __restrict__ idx2,
                                                float* __restrict__ w2) {
    __shared__ float4 smem4[1408];   // 22,528 B union
    const int id = blockIdx.x;
    if (id < 1024) {
        const int b  = id >> 8;
        const int nb = (id & 255) * 32;
        knn_tile<2048, 2>(xyz0, xyz1, 8192, b, nb, idx2, w2, smem4);
    } else if (id < 1280) {
        const int r  = id - 1024;
        const int b  = r >> 6;
        const int nb = (r & 63) * 32;
        knn_tile<512, 1>(xyz1, xyz2, 2048, b, nb, idx1, w1, smem4);
    } else if (id < 1536) {
        const int r  = id - 1280;
        const int b  = r >> 6;
        const int nb = (r & 7) * 64;
        const int cb = ((r >> 3) & 7) * 64;
        transpose_tile(x2, x2P, 512, 512, 512, b, nb, cb, smem4);
    } else {
        const int r  = id - 1536;
        const int b  = r >> 7;
        const int nb = (r & 31) * 64;
        const int cb = ((r >> 5) & 3) * 64;
        transpose_tile(x1, x1P, 256, 2048, 256, b, nb, cb, smem4);
    }
}

// ---------------------------------------------------------------------------
// K2: stage-1 interpolation, point-major OUTPUT (no transpose needed):
// featP2[b][n1][c] = sum_m w1_m * x2P[idx1_m][c], n1 over the 2048 mid
// points, c over 512 channels. vf4 gathers (lane=(chan-quad, point-group):
// one dwordx4 covers 4 points x 16 B); direct coalesced vf4 stores.
//   grid 1024 = b(4) x ntile(32) x ctile(8)
// ---------------------------------------------------------------------------
__global__ __launch_bounds__(256) void interp1_pm(const float* __restrict__ x2P,
                                                  const int* __restrict__ idx1,
                                                  const float* __restrict__ w1,
                                                  float* __restrict__ featP2) {
    __shared__ int   sj[3 * 64];
    __shared__ float sw[3 * 64];
    const int id = blockIdx.x;           // 0..1023
    const int b  = id >> 8;
    const int nt = (id >> 3) & 31;
    const int ct = id & 7;
    const int nb = nt * 64;
    const int cb = ct * 64;
    const int tid = threadIdx.x;

    if (tid < 192) {
        const int p = tid & 63, k = tid >> 6;
        sj[k * 64 + p] = idx1[(b * 3 + k) * 2048 + nb + p] * 512;  // row offset
        sw[k * 64 + p] = w1[(b * 3 + k) * 2048 + nb + p];
    }
    __syncthreads();

    const int q4 = tid & 15, pg = (tid >> 4) & 3, r = tid >> 6;
    const float* xb = x2P + (size_t)b * 512 * 512 + cb + q4 * 4;
    float* fb = featP2 + ((size_t)b * 2048 + nb) * 512 + cb + q4 * 4;
#pragma unroll
    for (int i = 0; i < 4; ++i) {
        const int p = i * 16 + r * 4 + pg;
        const vf4 acc = sw[0 * 64 + p] * ld4(xb + sj[0 * 64 + p])
                      + sw[1 * 64 + p] * ld4(xb + sj[1 * 64 + p])
                      + sw[2 * 64 + p] * ld4(xb + sj[2 * 64 + p]);
        *(vf4*)(fb + (size_t)p * 512) = acc;
    }
}

// ---------------------------------------------------------------------------
// K3: final output. x2-derived channels are a 3-GATHER of featP2 (random
// reads 604 -> 201 MB vs the composed 9-gather), x1 part and x0 copy
// unchanged. Plain stores (NT was neutral in R3/R4 A/B).
//   [   0,4096)  x2 part: (b, ntile128, ctile8) -> out ch 384..895
//   [4096,6144)  x1 part: (b, ntile128, ctile4) -> out ch 128..383
//   [6144,6400)  copy x0 -> out ch 0..127
// ---------------------------------------------------------------------------
__global__ __launch_bounds__(256) void k3_final(const float* __restrict__ x0,
                                                const float* __restrict__ x1P,
                                                const float* __restrict__ featP2,
                                                const int* __restrict__ idx2,
                                                const float* __restrict__ w2,
                                                float* __restrict__ out) {
    __shared__ float tile[64][68];       // rows 16B-aligned for vf4 writes
    __shared__ int   sj[3 * 64];
    __shared__ float sw[3 * 64];
    const int id  = blockIdx.x;
    const int tid = threadIdx.x;
    const int q4  = tid & 15;            // channel quad (4 ch)
    const int pg  = (tid >> 4) & 3;      // point sub-group
    const int r   = tid >> 6;            // wave

    if (id < 4096) {
        // ---------------- x2 channels: 3-gather of featP2 ----------------
        const int b   = id >> 10;
        const int rem = id & 1023;
        const int nt  = rem >> 3;        // 0..127
        const int ct  = rem & 7;         // 0..7
        const int nb  = nt * 64;
        const int cb  = ct * 64;

        if (tid < 192) {
            const int p = tid & 63, k = tid >> 6;
            sj[k * 64 + p] = idx2[(b * 3 + k) * 8192 + nb + p] * 512;
            sw[k * 64 + p] = w2[(b * 3 + k) * 8192 + nb + p];
        }
        __syncthreads();

        const float* xb = featP2 + (size_t)b * 2048 * 512 + cb + q4 * 4;
#pragma unroll
        for (int i = 0; i < 4; ++i) {
            const int p = i * 16 + r * 4 + pg;
            const vf4 acc = sw[0 * 64 + p] * ld4(xb + sj[0 * 64 + p])
                          + sw[1 * 64 + p] * ld4(xb + sj[1 * 64 + p])
                          + sw[2 * 64 + p] * ld4(xb + sj[2 * 64 + p]);
            *(vf4*)&tile[p][q4 * 4] = acc;
        }
        __syncthreads();
        {
            const int p2 = tid & 63;
#pragma unroll
            for (int i = 0; i < 16; ++i) {
                const int cl = r + 4 * i;
                out[((size_t)b * 896 + 384 + cb + cl) * 8192 + nb + p2] = tile[p2][cl];
            }
        }
    } else if (id < 6144) {
        // ---------------- x1 channels: 3-gather of x1P ----------------
        const int t   = id - 4096;
        const int b   = t >> 9;
        const int rem = t & 511;
        const int nt  = rem >> 2;        // 0..127
        const int ct  = rem & 3;         // 0..3
        const int nb  = nt * 64;
        const int cb  = ct * 64;

        if (tid < 192) {
            const int p = tid & 63, k = tid >> 6;
            sj[k * 64 + p] = idx2[(b * 3 + k) * 8192 + nb + p] * 256;
            sw[k * 64 + p] = w2[(b * 3 + k) * 8192 + nb + p];
        }
        __syncthreads();

        const float* xb = x1P + (size_t)b * 2048 * 256 + cb + q4 * 4;
#pragma unroll
        for (int i = 0; i < 4; ++i) {
            const int p = i * 16 + r * 4 + pg;
            const vf4 acc = sw[0 * 64 + p] * ld4(xb + sj[0 * 64 + p])
                          + sw[1 * 64 + p] * ld4(xb + sj[1 * 64 + p])
                          + sw[2 * 64 + p] * ld4(xb + sj[2 * 64 + p]);
            *(vf4*)&tile[p][q4 * 4] = acc;
        }
        __syncthreads();
        {
            const int p2 = tid & 63;
#pragma unroll
            for (int i = 0; i < 16; ++i) {
                const int cl = r + 4 * i;
                out[((size_t)b * 896 + 128 + cb + cl) * 8192 + nb + p2] = tile[p2][cl];
            }
        }
    } else {
        // ---------------- copy x0 -> out channels 0..127 ----------------
        const int rr = id - 6144;        // 0..255
        const int b  = rr >> 6;
        const int lb = rr & 63;
        const vf4* src = (const vf4*)x0;
        vf4* dst = (vf4*)out;
#pragma unroll
        for (int t2 = 0; t2 < 16; ++t2) {
            const int i = lb * 4096 + t2 * 256 + tid;    // 0..262143
            dst[(size_t)b * (896 * 2048) + i] = src[(size_t)b * (128 * 2048) + i];
        }
    }
}

extern "C" void kernel_launch(void* const* d_in, const int* in_sizes, int n_in,
                              void* d_out, int out_size, void* d_ws, size_t ws_size,
                              hipStream_t stream) {
    const float* xyz0 = (const float*)d_in[0];  // [4,8192,3]
    const float* xyz1 = (const float*)d_in[1];  // [4,2048,3]
    const float* xyz2 = (const float*)d_in[2];  // [4,512,3]
    const float* x0   = (const float*)d_in[3];  // [4,128,8192]
    const float* x1   = (const float*)d_in[4];  // [4,256,2048]
    const float* x2   = (const float*)d_in[5];  // [4,512,512]
    float* out = (float*)d_out;                 // [4,896,8192]

    // Workspace layout (bytes), total 30,343,168 (< 32.4 MB proven in R0):
    //   x1P    : float[4*2048*256] @ 0          (8,388,608)   point-major x1
    //   x2P    : float[4*512*512]  @ 8,388,608  (4,194,304)   point-major x2
    //   featP2 : float[4*2048*512] @ 12,582,912 (16,777,216)  stage-1 interp
    //   idx1   : int  [4*3*2048]   @ 29,360,128 (98,304)
    //   w1     : float[4*3*2048]   @ 29,458,432 (98,304)
    //   idx2   : int  [4*3*8192]   @ 29,556,736 (393,216)
    //   w2     : float[4*3*8192]   @ 29,949,952 (393,216)
    char* ws = (char*)d_ws;
    float* x1P    = (float*)(ws + 0);
    float* x2P    = (float*)(ws + 8388608);
    float* featP2 = (float*)(ws + 12582912);
    int*   idx1   = (int*)(ws + 29360128);
    float* w1     = (float*)(ws + 29458432);
    int*   idx2   = (int*)(ws + 29556736);
    float* w2     = (float*)(ws + 29949952);

    // K1: both KNNs + both point-major transposes (unchanged from R8).
    k1_stage<<<dim3(2048), 256, 0, stream>>>(xyz0, xyz1, xyz2, x1, x2,
                                             x1P, x2P, idx1, w1, idx2, w2);
    // K2: stage-1 interpolation -> featP2 (point-major, direct stores).
    interp1_pm<<<dim3(1024), 256, 0, stream>>>(x2P, idx1, w1, featP2);
    // K3: final output -- 3-gathers of featP2 and x1P + x0 copy.
    k3_final<<<dim3(6400), 256, 0, stream>>>(x0, x1P, featP2, idx2, w2, out);
}